// Round 6
// baseline (471.661 us; speedup 1.0000x reference)
//
#include <hip/hip_runtime.h>

#define NN 50000
#define EE 800000
#define HC 64
#define NB 782            // row buckets of 64 rows: 782*64 = 50048 >= NN
#define EB 256            // edge-pass blocks
#define EPB (EE / EB)     // 3125 edges per block, exact

__device__ __forceinline__ float dot4(float4 a, float4 b) {
    return fmaf(a.w, b.w, fmaf(a.z, b.z, fmaf(a.y, b.y, a.x * b.x)));
}
__device__ __forceinline__ void fma4(float& acc, float4 a, float4 b) {
    acc = fmaf(a.x, b.x, fmaf(a.y, b.y, fmaf(a.z, b.z, fmaf(a.w, b.w, acc))));
}

// ---------------------------------------------------------------------------
// Precompute fused attention vectors (tiny, 1 block):
//   v_lin[h][k]  = sum_c att_node[h,c] * W_lin[h*32+c][k]
//   v_topo[h][k] = sum_c att_topo[h,c] * W_topo[h*32+c][k]
//   cst[h]       = sum_c att_node*b_lin + att_topo*b_topo
// ---------------------------------------------------------------------------
__global__ __launch_bounds__(256) void precompute_k(
    const float* __restrict__ Wl, const float* __restrict__ bl,
    const float* __restrict__ Wt, const float* __restrict__ bt,
    const float* __restrict__ attn, const float* __restrict__ attt,
    float* __restrict__ fused)
{
    int tid = threadIdx.x;
    {
        int h = tid >> 7, k = tid & 127;
        float s = 0.f;
        for (int c = 0; c < 32; ++c)
            s = fmaf(attn[h * 32 + c], Wl[(h * 32 + c) * 128 + k], s);
        fused[h * 128 + k] = s;
    }
    if (tid < 128) {
        int h = tid >> 6, k = tid & 63;
        float s = 0.f;
        for (int c = 0; c < 32; ++c)
            s = fmaf(attt[h * 32 + c], Wt[(h * 32 + c) * 64 + k], s);
        fused[256 + h * 64 + k] = s;
    }
    if (tid < 2) {
        float s = 0.f;
        for (int c = 0; c < 32; ++c)
            s += attn[tid * 32 + c] * bl[tid * 32 + c]
               + attt[tid * 32 + c] * bt[tid * 32 + c];
        fused[384 + tid] = s;
    }
}

// ---------------------------------------------------------------------------
// score_k: es[n,h] = exp(lrelu( v_lin[h].x[n] + v_topo[h].topo[n] + cst[h] ))
// Fully coalesced; also emits the topo passthrough.
// ---------------------------------------------------------------------------
__global__ __launch_bounds__(256) void score_k(
    const float* __restrict__ x, const float* __restrict__ topo,
    const float* __restrict__ fused, float* __restrict__ es,
    float* __restrict__ topo_out)
{
    const float4* x4  = (const float4*)x;
    const float4* t4  = (const float4*)topo;
    const float4* vl4 = (const float4*)fused;          // [2][32]
    const float4* vt4 = (const float4*)(fused + 256);  // [2][16]
    float4* to4 = (float4*)topo_out;
    int tid = threadIdx.x, l = tid & 63;
    float4 vA0 = vl4[l & 31], vA1 = vl4[32 + (l & 31)];
    float4 vT0 = vt4[l & 15], vT1 = vt4[16 + (l & 15)];
    float c0 = fused[384], c1 = fused[385];
    int w = blockIdx.x * 4 + (tid >> 6);   // wave id; 16 nodes per wave
#pragma unroll
    for (int q = 0; q < 4; ++q) {
        int n0 = w * 16 + q * 4;
        if (n0 >= NN) return;
        float4 A1 = x4[n0 * 32 + l];         // rows n0, n0+1
        float4 A2 = x4[(n0 + 2) * 32 + l];   // rows n0+2, n0+3
        float4 B  = t4[n0 * 16 + l];         // rows n0..n0+3
        to4[n0 * 16 + l] = B;                // passthrough output 1
        float p10 = dot4(A1, vA0), p11 = dot4(A1, vA1);
        float p20 = dot4(A2, vA0), p21 = dot4(A2, vA1);
        float q0  = dot4(B,  vT0), q1  = dot4(B,  vT1);
#pragma unroll
        for (int d = 16; d >= 1; d >>= 1) {
            p10 += __shfl_xor(p10, d, 64); p11 += __shfl_xor(p11, d, 64);
            p20 += __shfl_xor(p20, d, 64); p21 += __shfl_xor(p21, d, 64);
        }
#pragma unroll
        for (int d = 8; d >= 1; d >>= 1) {
            q0 += __shfl_xor(q0, d, 64); q1 += __shfl_xor(q1, d, 64);
        }
        float x00=__shfl(p10,0), x10=__shfl(p10,32), x20=__shfl(p20,0), x30=__shfl(p20,32);
        float x01=__shfl(p11,0), x11=__shfl(p11,32), x21=__shfl(p21,0), x31=__shfl(p21,32);
        float q00=__shfl(q0,0),  q10=__shfl(q0,16),  q20=__shfl(q0,32), q30=__shfl(q0,48);
        float q01=__shfl(q1,0),  q11=__shfl(q1,16),  q21=__shfl(q1,32), q31=__shfl(q1,48);
        if (l < 8) {
            int j = l >> 1, h = l & 1;
            float xs, qs, cs;
            if (h) { xs = j==0?x01:j==1?x11:j==2?x21:x31;
                     qs = j==0?q01:j==1?q11:j==2?q21:q31; cs = c1; }
            else   { xs = j==0?x00:j==1?x10:j==2?x20:x30;
                     qs = j==0?q00:j==1?q10:j==2?q20:q30; cs = c0; }
            float s = xs + qs + cs;
            float lr = s > 0.f ? s : 0.2f * s;
            es[(n0 + j) * 2 + h] = __expf(lr);
        }
    }
}

// ---------------------------------------------------------------------------
// edge_count_k: one edge pass per block (EPB edges), zero global atomics.
//  - per-(block,bucket) edge counts in LDS (u32, LDS atomics), bucket=row>>6
//    written as cnt[b*EB + blk] (coalesced for the scan kernel).
//  - softmax denominator partials: s_h += es[col[e],h]
// ---------------------------------------------------------------------------
__global__ __launch_bounds__(256) void edge_count_k(
    const int* __restrict__ eidx, const float* __restrict__ es,
    unsigned* __restrict__ cnt, float* __restrict__ part_sum)
{
    __shared__ unsigned bcnt[NB];
    int tid = threadIdx.x, blk = blockIdx.x;
    for (int i = tid; i < NB; i += 256) bcnt[i] = 0u;
    __syncthreads();

    const float2* es2 = (const float2*)es;
    int e0 = blk * EPB;
    float s0 = 0.f, s1 = 0.f;
    for (int e = e0 + tid; e < e0 + EPB; e += 256) {
        int r = eidx[e];
        int c = eidx[EE + e];
        atomicAdd(&bcnt[r >> 6], 1u);
        float2 ev = es2[c];
        s0 += ev.x; s1 += ev.y;
    }
#pragma unroll
    for (int d = 32; d; d >>= 1) {
        s0 += __shfl_xor(s0, d, 64);
        s1 += __shfl_xor(s1, d, 64);
    }
    __shared__ float sh[8];
    if ((tid & 63) == 0) { sh[(tid >> 6) * 2] = s0; sh[(tid >> 6) * 2 + 1] = s1; }
    __syncthreads();
    if (tid == 0) {
        for (int j = 1; j < 4; ++j) { s0 += sh[2 * j]; s1 += sh[2 * j + 1]; }
        part_sum[blk * 2] = s0; part_sum[blk * 2 + 1] = s1;
    }
    for (int i = tid; i < NB; i += 256) cnt[(size_t)i * EB + blk] = bcnt[i];
}

// ---------------------------------------------------------------------------
// base1_k: per bucket b, exclusive scan of cnt[b][0..255] over blocks
//          -> base_local[b][blk]; total[b] = bucket edge count.
// ---------------------------------------------------------------------------
__global__ __launch_bounds__(256) void base1_k(
    const unsigned* __restrict__ cnt, unsigned* __restrict__ base_local,
    unsigned* __restrict__ total)
{
    int b = blockIdx.x, tid = threadIdx.x, lane = tid & 63, wid = tid >> 6;
    unsigned v = cnt[(size_t)b * EB + tid], orig = v;
#pragma unroll
    for (int d = 1; d < 64; d <<= 1) {
        unsigned t = __shfl_up(v, d, 64);
        if (lane >= d) v += t;
    }
    __shared__ unsigned wtot[4];
    if (lane == 63) wtot[wid] = v;
    __syncthreads();
    unsigned wpre = 0;
    for (int j = 0; j < wid; ++j) wpre += wtot[j];
    base_local[(size_t)b * EB + tid] = wpre + v - orig;
    if (tid == 255) total[b] = wpre + v;
}

// ---------------------------------------------------------------------------
// base2_k: single block (1024 thr): exclusive scan total[NB] -> bucket_start
//          (+ sentinel bucket_start[NB]=EE); then reduce part_sum -> gstat.
// ---------------------------------------------------------------------------
__global__ __launch_bounds__(1024) void base2_k(
    const unsigned* __restrict__ total, const float* __restrict__ part_sum,
    unsigned* __restrict__ bucket_start, float* __restrict__ gstat)
{
    int tid = threadIdx.x, lane = tid & 63, wid = tid >> 6;
    unsigned v = (tid < NB) ? total[tid] : 0u, orig = v;
#pragma unroll
    for (int d = 1; d < 64; d <<= 1) {
        unsigned t = __shfl_up(v, d, 64);
        if (lane >= d) v += t;
    }
    __shared__ unsigned wtot[16];
    if (lane == 63) wtot[wid] = v;
    __syncthreads();
    unsigned wpre = 0;
    for (int j = 0; j < wid; ++j) wpre += wtot[j];
    if (tid < NB) {
        unsigned excl = wpre + v - orig;
        bucket_start[tid] = excl;
        if (tid == NB - 1) bucket_start[NB] = excl + orig;
    }
    // ---- phase 2: gstat ----
    float s0 = 0.f, s1 = 0.f;
    if (tid < EB) { s0 = part_sum[tid * 2]; s1 = part_sum[tid * 2 + 1]; }
#pragma unroll
    for (int d = 32; d; d >>= 1) {
        s0 += __shfl_xor(s0, d, 64);
        s1 += __shfl_xor(s1, d, 64);
    }
    __shared__ float sh2[32];
    if (lane == 0) { sh2[wid * 2] = s0; sh2[wid * 2 + 1] = s1; }
    __syncthreads();
    if (tid == 0) {
        for (int j = 1; j < 4; ++j) { s0 += sh2[2 * j]; s1 += sh2[2 * j + 1]; }
        gstat[0] = 1.f / s0; gstat[1] = 1.f / s1;
    }
}

// ---------------------------------------------------------------------------
// bin_k: place each edge's packed (row<<16)|col into its bucket window.
// Zero global atomics: per-bucket LDS cursors seeded from bucket_start +
// base_local. Writes are ~8-sequential-slot streams per (block,bucket).
// ---------------------------------------------------------------------------
__global__ __launch_bounds__(256) void bin_k(
    const int* __restrict__ eidx, const unsigned* __restrict__ bucket_start,
    const unsigned* __restrict__ base_local, unsigned* __restrict__ binned)
{
    __shared__ unsigned cur[NB];
    int tid = threadIdx.x, blk = blockIdx.x;
    for (int i = tid; i < NB; i += 256)
        cur[i] = bucket_start[i] + base_local[(size_t)i * EB + blk];
    __syncthreads();
    int e0 = blk * EPB;
    for (int e = e0 + tid; e < e0 + EPB; e += 256) {
        unsigned r = (unsigned)eidx[e];
        unsigned c = (unsigned)eidx[EE + e];
        unsigned slot = atomicAdd(&cur[r >> 6], 1u);   // LDS atomic
        binned[slot] = (r << 16) | c;
    }
}

// ---------------------------------------------------------------------------
// gemm_scale_k: w[n,c] = (x[n]·W_lin[c] + b_lin[c]) * es[n,h]/denom_h
// Wave = 64 channels x 8 nodes. Weights in LDS, row stride 132 floats.
// ---------------------------------------------------------------------------
__global__ __launch_bounds__(256) void gemm_scale_k(
    const float* __restrict__ x, const float* __restrict__ Wl,
    const float* __restrict__ bl, const float* __restrict__ es,
    const float* __restrict__ gstat, float* __restrict__ wout)
{
    __shared__ float WLs[64 * 132];   // 33.8 KB
    int tid = threadIdx.x;
    const float4* Wl4 = (const float4*)Wl;
    for (int i = tid; i < 2048; i += 256) {
        float4 v = Wl4[i];
        *(float4*)&WLs[(i >> 5) * 132 + ((i & 31) << 2)] = v;
    }
    __syncthreads();

    int cl = tid & 63;
    int n0 = (blockIdx.x * 4 + (tid >> 6)) * 8;
    if (n0 >= NN) return;
    const float4* xp = (const float4*)(x + (size_t)n0 * 128);
    float b = bl[cl];
    float a0=b,a1=b,a2=b,a3=b,a4=b,a5=b,a6=b,a7=b;
#pragma unroll 2
    for (int k4 = 0; k4 < 32; ++k4) {
        float4 wf = *(const float4*)&WLs[cl * 132 + (k4 << 2)];
        float4 v0 = xp[k4],        v1 = xp[32 + k4];
        float4 v2 = xp[64 + k4],   v3 = xp[96 + k4];
        float4 v4 = xp[128 + k4],  v5 = xp[160 + k4];
        float4 v6 = xp[192 + k4],  v7 = xp[224 + k4];
        fma4(a0, wf, v0); fma4(a1, wf, v1); fma4(a2, wf, v2); fma4(a3, wf, v3);
        fma4(a4, wf, v4); fma4(a5, wf, v5); fma4(a6, wf, v6); fma4(a7, wf, v7);
    }
    int h = cl >> 5;
    float gi = gstat[h];
    size_t ob = (size_t)n0 * 64 + cl;
    wout[ob      ] = a0 * (es[(n0+0)*2+h] * gi);
    wout[ob +  64] = a1 * (es[(n0+1)*2+h] * gi);
    wout[ob + 128] = a2 * (es[(n0+2)*2+h] * gi);
    wout[ob + 192] = a3 * (es[(n0+3)*2+h] * gi);
    wout[ob + 256] = a4 * (es[(n0+4)*2+h] * gi);
    wout[ob + 320] = a5 * (es[(n0+5)*2+h] * gi);
    wout[ob + 384] = a6 * (es[(n0+6)*2+h] * gi);
    wout[ob + 448] = a7 * (es[(n0+7)*2+h] * gi);
}

// ---------------------------------------------------------------------------
// fused_agg_k: one block per 64-row bucket. LDS fp32 accumulator (16KB),
// stream binned edges coalesced, gather w 256B-coalesced with 8-edge ILP,
// ds_add_f32 accumulate, coalesced out write (+bias). No CSR, no atomics
// to global memory. Rows without edges get bias.
// ---------------------------------------------------------------------------
__global__ __launch_bounds__(256) void fused_agg_k(
    const float* __restrict__ wsrc, const unsigned* __restrict__ binned,
    const unsigned* __restrict__ bucket_start, const float* __restrict__ bias,
    float* __restrict__ out)
{
    __shared__ float acc[64 * 64];   // 16 KB
    int tid = threadIdx.x, lane = tid & 63, w = tid >> 6;
    int b = blockIdx.x, r0 = b << 6;
    for (int i = tid; i < 4096; i += 256) acc[i] = 0.f;
    __syncthreads();

    unsigned start = bucket_start[b], end = bucket_start[b + 1];
    for (unsigned base2 = start + w * 8u; base2 < end; base2 += 32u) {
        int m = (int)min(8u, end - base2);
        unsigned idx = base2 + (unsigned)(lane & 7);
        unsigned ev = binned[idx < end ? idx : end - 1];
        float wv[8]; int li[8];
#pragma unroll
        for (int j = 0; j < 8; ++j) {
            if (j < m) {
                unsigned e = __shfl(ev, j, 64);
                li[j] = (((int)(e >> 16) - r0) << 6) + lane;
                wv[j] = wsrc[(size_t)(e & 0xffffu) * 64 + lane];
            }
        }
#pragma unroll
        for (int j = 0; j < 8; ++j)
            if (j < m) atomicAdd(&acc[li[j]], wv[j]);
    }
    __syncthreads();

    for (int i = tid; i < 4096; i += 256) {
        int r = r0 + (i >> 6);
        if (r < NN) out[(size_t)r * 64 + (i & 63)] = acc[i] + bias[i & 63];
    }
}

// ---------------------------------------------------------------------------
extern "C" void kernel_launch(void* const* d_in, const int* in_sizes, int n_in,
                              void* d_out, int out_size, void* d_ws, size_t ws_size,
                              hipStream_t stream)
{
    const float* x    = (const float*)d_in[0];
    const int*   eidx = (const int*)d_in[1];
    const float* topo = (const float*)d_in[2];
    const float* Wl   = (const float*)d_in[3];
    const float* bl   = (const float*)d_in[4];
    const float* Wt   = (const float*)d_in[5];
    const float* bt   = (const float*)d_in[6];
    const float* attn = (const float*)d_in[7];
    const float* attt = (const float*)d_in[8];
    const float* bias = (const float*)d_in[9];
    float* out = (float*)d_out;

    char* p = (char*)d_ws;
    auto alloc = [&](size_t bytes) {
        char* r = p;
        p += (bytes + 511) & ~size_t(511);
        return r;
    };
    float*    wbuf      = (float*)   alloc((size_t)NN * HC * sizeof(float));   // 12.8 MB
    float*    es        = (float*)   alloc((size_t)NN * 2 * sizeof(float));    // 400 KB
    unsigned* binned    = (unsigned*)alloc((size_t)EE * sizeof(unsigned));     // 3.2 MB
    unsigned* cnt       = (unsigned*)alloc((size_t)NB * EB * sizeof(unsigned));// 0.8 MB
    unsigned* base_loc  = (unsigned*)alloc((size_t)NB * EB * sizeof(unsigned));// 0.8 MB
    unsigned* total     = (unsigned*)alloc((size_t)NB * sizeof(unsigned));
    unsigned* bstart    = (unsigned*)alloc((size_t)(NB + 1) * sizeof(unsigned));
    float*    part_sum  = (float*)   alloc(EB * 2 * sizeof(float));
    float*    gstat     = (float*)   alloc(4 * sizeof(float));
    float*    fused     = (float*)   alloc(512 * sizeof(float));

    precompute_k<<<1, 256, 0, stream>>>(Wl, bl, Wt, bt, attn, attt, fused);
    score_k<<<782, 256, 0, stream>>>(x, topo, fused, es, out + (size_t)NN * HC);
    edge_count_k<<<EB, 256, 0, stream>>>(eidx, es, cnt, part_sum);
    base1_k<<<NB, 256, 0, stream>>>(cnt, base_loc, total);
    base2_k<<<1, 1024, 0, stream>>>(total, part_sum, bstart, gstat);
    bin_k<<<EB, 256, 0, stream>>>(eidx, bstart, base_loc, binned);
    gemm_scale_k<<<(NN + 31) / 32, 256, 0, stream>>>(x, Wl, bl, es, gstat, wbuf);
    fused_agg_k<<<NB, 256, 0, stream>>>(wbuf, binned, bstart, bias, out);
}

// Round 7
// 131.230 us; speedup vs baseline: 3.5942x; 3.5942x over previous
//
#include <hip/hip_runtime.h>

#define NN 50000
#define EE 800000
#define HC 64
#define NB 782            // row buckets of 64 rows: 782*64 = 50048 >= NN
#define EB 256            // edge-pass blocks
#define EPB (EE / EB)     // 3125 edges per block, exact
#define BUCKET_CAP 2048   // mean bucket = 1024, sd 32; 2048 = +32 sigma

__device__ __forceinline__ float dot4(float4 a, float4 b) {
    return fmaf(a.w, b.w, fmaf(a.z, b.z, fmaf(a.y, b.y, a.x * b.x)));
}
__device__ __forceinline__ void fma4(float& acc, float4 a, float4 b) {
    acc = fmaf(a.x, b.x, fmaf(a.y, b.y, fmaf(a.z, b.z, fmaf(a.w, b.w, acc))));
}

// ---------------------------------------------------------------------------
// Precompute fused attention vectors (tiny, 1 block)
// ---------------------------------------------------------------------------
__global__ __launch_bounds__(256) void precompute_k(
    const float* __restrict__ Wl, const float* __restrict__ bl,
    const float* __restrict__ Wt, const float* __restrict__ bt,
    const float* __restrict__ attn, const float* __restrict__ attt,
    float* __restrict__ fused)
{
    int tid = threadIdx.x;
    {
        int h = tid >> 7, k = tid & 127;
        float s = 0.f;
        for (int c = 0; c < 32; ++c)
            s = fmaf(attn[h * 32 + c], Wl[(h * 32 + c) * 128 + k], s);
        fused[h * 128 + k] = s;
    }
    if (tid < 128) {
        int h = tid >> 6, k = tid & 63;
        float s = 0.f;
        for (int c = 0; c < 32; ++c)
            s = fmaf(attt[h * 32 + c], Wt[(h * 32 + c) * 64 + k], s);
        fused[256 + h * 64 + k] = s;
    }
    if (tid < 2) {
        float s = 0.f;
        for (int c = 0; c < 32; ++c)
            s += attn[tid * 32 + c] * bl[tid * 32 + c]
               + attt[tid * 32 + c] * bt[tid * 32 + c];
        fused[384 + tid] = s;
    }
}

// ---------------------------------------------------------------------------
// score_k: es[n,h] = exp(lrelu( v_lin[h].x[n] + v_topo[h].topo[n] + cst[h] ))
// Fully coalesced; also emits the topo passthrough.
// ---------------------------------------------------------------------------
__global__ __launch_bounds__(256) void score_k(
    const float* __restrict__ x, const float* __restrict__ topo,
    const float* __restrict__ fused, float* __restrict__ es,
    float* __restrict__ topo_out)
{
    const float4* x4  = (const float4*)x;
    const float4* t4  = (const float4*)topo;
    const float4* vl4 = (const float4*)fused;          // [2][32]
    const float4* vt4 = (const float4*)(fused + 256);  // [2][16]
    float4* to4 = (float4*)topo_out;
    int tid = threadIdx.x, l = tid & 63;
    float4 vA0 = vl4[l & 31], vA1 = vl4[32 + (l & 31)];
    float4 vT0 = vt4[l & 15], vT1 = vt4[16 + (l & 15)];
    float c0 = fused[384], c1 = fused[385];
    int w = blockIdx.x * 4 + (tid >> 6);   // wave id; 16 nodes per wave
#pragma unroll
    for (int q = 0; q < 4; ++q) {
        int n0 = w * 16 + q * 4;
        if (n0 >= NN) return;
        float4 A1 = x4[n0 * 32 + l];         // rows n0, n0+1
        float4 A2 = x4[(n0 + 2) * 32 + l];   // rows n0+2, n0+3
        float4 B  = t4[n0 * 16 + l];         // rows n0..n0+3
        to4[n0 * 16 + l] = B;                // passthrough output 1
        float p10 = dot4(A1, vA0), p11 = dot4(A1, vA1);
        float p20 = dot4(A2, vA0), p21 = dot4(A2, vA1);
        float q0  = dot4(B,  vT0), q1  = dot4(B,  vT1);
#pragma unroll
        for (int d = 16; d >= 1; d >>= 1) {
            p10 += __shfl_xor(p10, d, 64); p11 += __shfl_xor(p11, d, 64);
            p20 += __shfl_xor(p20, d, 64); p21 += __shfl_xor(p21, d, 64);
        }
#pragma unroll
        for (int d = 8; d >= 1; d >>= 1) {
            q0 += __shfl_xor(q0, d, 64); q1 += __shfl_xor(q1, d, 64);
        }
        float x00=__shfl(p10,0), x10=__shfl(p10,32), x20=__shfl(p20,0), x30=__shfl(p20,32);
        float x01=__shfl(p11,0), x11=__shfl(p11,32), x21=__shfl(p21,0), x31=__shfl(p21,32);
        float q00=__shfl(q0,0),  q10=__shfl(q0,16),  q20=__shfl(q0,32), q30=__shfl(q0,48);
        float q01=__shfl(q1,0),  q11=__shfl(q1,16),  q21=__shfl(q1,32), q31=__shfl(q1,48);
        if (l < 8) {
            int j = l >> 1, h = l & 1;
            float xs, qs, cs;
            if (h) { xs = j==0?x01:j==1?x11:j==2?x21:x31;
                     qs = j==0?q01:j==1?q11:j==2?q21:q31; cs = c1; }
            else   { xs = j==0?x00:j==1?x10:j==2?x20:x30;
                     qs = j==0?q00:j==1?q10:j==2?q20:q30; cs = c0; }
            float s = xs + qs + cs;
            float lr = s > 0.f ? s : 0.2f * s;
            es[(n0 + j) * 2 + h] = __expf(lr);
        }
    }
}

// ---------------------------------------------------------------------------
// edge_count_k: one edge pass per block, zero global atomics.
//  - per-(block,bucket) edge counts in LDS; bucket = row>>6
//  - softmax denominator partials: s_h += es[col[e],h]
// ---------------------------------------------------------------------------
__global__ __launch_bounds__(256) void edge_count_k(
    const int* __restrict__ eidx, const float* __restrict__ es,
    unsigned* __restrict__ cnt, float* __restrict__ part_sum)
{
    __shared__ unsigned bcnt[NB];
    int tid = threadIdx.x, blk = blockIdx.x;
    for (int i = tid; i < NB; i += 256) bcnt[i] = 0u;
    __syncthreads();

    const float2* es2 = (const float2*)es;
    int e0 = blk * EPB;
    float s0 = 0.f, s1 = 0.f;
    for (int e = e0 + tid; e < e0 + EPB; e += 256) {
        int r = eidx[e];
        int c = eidx[EE + e];
        atomicAdd(&bcnt[r >> 6], 1u);
        float2 ev = es2[c];
        s0 += ev.x; s1 += ev.y;
    }
#pragma unroll
    for (int d = 32; d; d >>= 1) {
        s0 += __shfl_xor(s0, d, 64);
        s1 += __shfl_xor(s1, d, 64);
    }
    __shared__ float sh[8];
    if ((tid & 63) == 0) { sh[(tid >> 6) * 2] = s0; sh[(tid >> 6) * 2 + 1] = s1; }
    __syncthreads();
    if (tid == 0) {
        for (int j = 1; j < 4; ++j) { s0 += sh[2 * j]; s1 += sh[2 * j + 1]; }
        part_sum[blk * 2] = s0; part_sum[blk * 2 + 1] = s1;
    }
    for (int i = tid; i < NB; i += 256) cnt[(size_t)i * EB + blk] = bcnt[i];
}

// ---------------------------------------------------------------------------
// base1_k: per bucket b, exclusive scan of cnt[b][0..255] -> base_local;
//          total[b] = bucket edge count.
// ---------------------------------------------------------------------------
__global__ __launch_bounds__(256) void base1_k(
    const unsigned* __restrict__ cnt, unsigned* __restrict__ base_local,
    unsigned* __restrict__ total)
{
    int b = blockIdx.x, tid = threadIdx.x, lane = tid & 63, wid = tid >> 6;
    unsigned v = cnt[(size_t)b * EB + tid], orig = v;
#pragma unroll
    for (int d = 1; d < 64; d <<= 1) {
        unsigned t = __shfl_up(v, d, 64);
        if (lane >= d) v += t;
    }
    __shared__ unsigned wtot[4];
    if (lane == 63) wtot[wid] = v;
    __syncthreads();
    unsigned wpre = 0;
    for (int j = 0; j < wid; ++j) wpre += wtot[j];
    base_local[(size_t)b * EB + tid] = wpre + v - orig;
    if (tid == 255) total[b] = wpre + v;
}

// ---------------------------------------------------------------------------
// base2_k: single block: exclusive scan total[NB] -> bucket_start (+sentinel);
//          reduce part_sum -> gstat.
// ---------------------------------------------------------------------------
__global__ __launch_bounds__(1024) void base2_k(
    const unsigned* __restrict__ total, const float* __restrict__ part_sum,
    unsigned* __restrict__ bucket_start, float* __restrict__ gstat)
{
    int tid = threadIdx.x, lane = tid & 63, wid = tid >> 6;
    unsigned v = (tid < NB) ? total[tid] : 0u, orig = v;
#pragma unroll
    for (int d = 1; d < 64; d <<= 1) {
        unsigned t = __shfl_up(v, d, 64);
        if (lane >= d) v += t;
    }
    __shared__ unsigned wtot[16];
    if (lane == 63) wtot[wid] = v;
    __syncthreads();
    unsigned wpre = 0;
    for (int j = 0; j < wid; ++j) wpre += wtot[j];
    if (tid < NB) {
        unsigned excl = wpre + v - orig;
        bucket_start[tid] = excl;
        if (tid == NB - 1) bucket_start[NB] = excl + orig;
    }
    float s0 = 0.f, s1 = 0.f;
    if (tid < EB) { s0 = part_sum[tid * 2]; s1 = part_sum[tid * 2 + 1]; }
#pragma unroll
    for (int d = 32; d; d >>= 1) {
        s0 += __shfl_xor(s0, d, 64);
        s1 += __shfl_xor(s1, d, 64);
    }
    __shared__ float sh2[32];
    if (lane == 0) { sh2[wid * 2] = s0; sh2[wid * 2 + 1] = s1; }
    __syncthreads();
    if (tid == 0) {
        for (int j = 1; j < 4; ++j) { s0 += sh2[2 * j]; s1 += sh2[2 * j + 1]; }
        gstat[0] = 1.f / s0; gstat[1] = 1.f / s1;
    }
}

// ---------------------------------------------------------------------------
// bin_k: place each edge's packed (row<<16)|col into its bucket window.
// LDS cursors only; writes are short sequential streams per (block,bucket).
// ---------------------------------------------------------------------------
__global__ __launch_bounds__(256) void bin_k(
    const int* __restrict__ eidx, const unsigned* __restrict__ bucket_start,
    const unsigned* __restrict__ base_local, unsigned* __restrict__ binned)
{
    __shared__ unsigned cur[NB];
    int tid = threadIdx.x, blk = blockIdx.x;
    for (int i = tid; i < NB; i += 256)
        cur[i] = bucket_start[i] + base_local[(size_t)i * EB + blk];
    __syncthreads();
    int e0 = blk * EPB;
    for (int e = e0 + tid; e < e0 + EPB; e += 256) {
        unsigned r = (unsigned)eidx[e];
        unsigned c = (unsigned)eidx[EE + e];
        unsigned slot = atomicAdd(&cur[r >> 6], 1u);   // LDS atomic
        binned[slot] = (r << 16) | c;
    }
}

// ---------------------------------------------------------------------------
// gemm_scale_k: w[n,c] = (x[n]·W_lin[c] + b_lin[c]) * es[n,h]/denom_h
// ---------------------------------------------------------------------------
__global__ __launch_bounds__(256) void gemm_scale_k(
    const float* __restrict__ x, const float* __restrict__ Wl,
    const float* __restrict__ bl, const float* __restrict__ es,
    const float* __restrict__ gstat, float* __restrict__ wout)
{
    __shared__ float WLs[64 * 132];   // 33.8 KB
    int tid = threadIdx.x;
    const float4* Wl4 = (const float4*)Wl;
    for (int i = tid; i < 2048; i += 256) {
        float4 v = Wl4[i];
        *(float4*)&WLs[(i >> 5) * 132 + ((i & 31) << 2)] = v;
    }
    __syncthreads();

    int cl = tid & 63;
    int n0 = (blockIdx.x * 4 + (tid >> 6)) * 8;
    if (n0 >= NN) return;
    const float4* xp = (const float4*)(x + (size_t)n0 * 128);
    float b = bl[cl];
    float a0=b,a1=b,a2=b,a3=b,a4=b,a5=b,a6=b,a7=b;
#pragma unroll 2
    for (int k4 = 0; k4 < 32; ++k4) {
        float4 wf = *(const float4*)&WLs[cl * 132 + (k4 << 2)];
        float4 v0 = xp[k4],        v1 = xp[32 + k4];
        float4 v2 = xp[64 + k4],   v3 = xp[96 + k4];
        float4 v4 = xp[128 + k4],  v5 = xp[160 + k4];
        float4 v6 = xp[192 + k4],  v7 = xp[224 + k4];
        fma4(a0, wf, v0); fma4(a1, wf, v1); fma4(a2, wf, v2); fma4(a3, wf, v3);
        fma4(a4, wf, v4); fma4(a5, wf, v5); fma4(a6, wf, v6); fma4(a7, wf, v7);
    }
    int h = cl >> 5;
    float gi = gstat[h];
    size_t ob = (size_t)n0 * 64 + cl;
    wout[ob      ] = a0 * (es[(n0+0)*2+h] * gi);
    wout[ob +  64] = a1 * (es[(n0+1)*2+h] * gi);
    wout[ob + 128] = a2 * (es[(n0+2)*2+h] * gi);
    wout[ob + 192] = a3 * (es[(n0+3)*2+h] * gi);
    wout[ob + 256] = a4 * (es[(n0+4)*2+h] * gi);
    wout[ob + 320] = a5 * (es[(n0+5)*2+h] * gi);
    wout[ob + 384] = a6 * (es[(n0+6)*2+h] * gi);
    wout[ob + 448] = a7 * (es[(n0+7)*2+h] * gi);
}

// ---------------------------------------------------------------------------
// sort_agg_k: one block (512 thr / 8 waves) per 64-row bucket.
//   1) stage bucket edges in LDS, 64-bin row histogram (LDS atomics),
//      wave-0 shfl scan, counting-sort cols into row-sorted u16 list.
//   2) wave w owns rows 8w..8w+7 exclusively: register accumulation
//      (lane=channel, 4-deep ILP coalesced 256B gathers), direct out write.
// No global atomics, no LDS accumulate, no register arrays.
// ---------------------------------------------------------------------------
__global__ __launch_bounds__(512) void sort_agg_k(
    const float* __restrict__ wsrc, const unsigned* __restrict__ binned,
    const unsigned* __restrict__ bucket_start, const float* __restrict__ bias,
    float* __restrict__ out)
{
    __shared__ unsigned ecol[BUCKET_CAP];        // 8 KB packed (r<<16)|c
    __shared__ unsigned short scol[BUCKET_CAP];  // 4 KB row-sorted cols
    __shared__ unsigned hist[65];                // cursor during placement
    __shared__ unsigned rbase[65];               // exclusive row offsets
    int tid = threadIdx.x, lane = tid & 63, w = tid >> 6;
    int b = blockIdx.x, r0 = b << 6;
    unsigned start = bucket_start[b], end = bucket_start[b + 1];
    int m = (int)(end - start);

    if (tid < 65) hist[tid] = 0u;
    __syncthreads();
    for (int i = tid; i < m; i += 512) {
        unsigned e = binned[start + i];
        ecol[i] = e;
        atomicAdd(&hist[(e >> 16) - (unsigned)r0], 1u);
    }
    __syncthreads();
    if (tid < 64) {   // wave 0: exclusive scan of 64 row counts
        unsigned v = hist[tid], xv = v;
#pragma unroll
        for (int d = 1; d < 64; d <<= 1) {
            unsigned t = __shfl_up(xv, d, 64);
            if (lane >= d) xv += t;
        }
        rbase[tid] = xv - v;
        hist[tid] = xv - v;        // reuse as placement cursor
        if (tid == 63) rbase[64] = xv;
    }
    __syncthreads();
    for (int i = tid; i < m; i += 512) {
        unsigned e = ecol[i];
        unsigned slot = atomicAdd(&hist[(e >> 16) - (unsigned)r0], 1u);
        scol[slot] = (unsigned short)(e & 0xffffu);
    }
    __syncthreads();

    float bv = bias[lane];
    for (int rr = w * 8; rr < w * 8 + 8; ++rr) {
        int r = r0 + rr;
        if (r >= NN) break;
        unsigned st = rbase[rr], en = rbase[rr + 1];
        float acc = 0.f;
        unsigned j = st;
        for (; j + 4 <= en; j += 4) {
            unsigned c0 = scol[j],     c1 = scol[j + 1];
            unsigned c2 = scol[j + 2], c3 = scol[j + 3];
            acc += wsrc[(size_t)c0 * 64 + lane];
            acc += wsrc[(size_t)c1 * 64 + lane];
            acc += wsrc[(size_t)c2 * 64 + lane];
            acc += wsrc[(size_t)c3 * 64 + lane];
        }
        for (; j < en; ++j) acc += wsrc[(size_t)scol[j] * 64 + lane];
        out[(size_t)r * 64 + lane] = acc + bv;
    }
}

// ---------------------------------------------------------------------------
extern "C" void kernel_launch(void* const* d_in, const int* in_sizes, int n_in,
                              void* d_out, int out_size, void* d_ws, size_t ws_size,
                              hipStream_t stream)
{
    const float* x    = (const float*)d_in[0];
    const int*   eidx = (const int*)d_in[1];
    const float* topo = (const float*)d_in[2];
    const float* Wl   = (const float*)d_in[3];
    const float* bl   = (const float*)d_in[4];
    const float* Wt   = (const float*)d_in[5];
    const float* bt   = (const float*)d_in[6];
    const float* attn = (const float*)d_in[7];
    const float* attt = (const float*)d_in[8];
    const float* bias = (const float*)d_in[9];
    float* out = (float*)d_out;

    char* p = (char*)d_ws;
    auto alloc = [&](size_t bytes) {
        char* r = p;
        p += (bytes + 511) & ~size_t(511);
        return r;
    };
    float*    wbuf      = (float*)   alloc((size_t)NN * HC * sizeof(float));   // 12.8 MB
    float*    es        = (float*)   alloc((size_t)NN * 2 * sizeof(float));    // 400 KB
    unsigned* binned    = (unsigned*)alloc((size_t)EE * sizeof(unsigned));     // 3.2 MB
    unsigned* cnt       = (unsigned*)alloc((size_t)NB * EB * sizeof(unsigned));// 0.8 MB
    unsigned* base_loc  = (unsigned*)alloc((size_t)NB * EB * sizeof(unsigned));// 0.8 MB
    unsigned* total     = (unsigned*)alloc((size_t)NB * sizeof(unsigned));
    unsigned* bstart    = (unsigned*)alloc((size_t)(NB + 1) * sizeof(unsigned));
    float*    part_sum  = (float*)   alloc(EB * 2 * sizeof(float));
    float*    gstat     = (float*)   alloc(4 * sizeof(float));
    float*    fused     = (float*)   alloc(512 * sizeof(float));

    precompute_k<<<1, 256, 0, stream>>>(Wl, bl, Wt, bt, attn, attt, fused);
    score_k<<<782, 256, 0, stream>>>(x, topo, fused, es, out + (size_t)NN * HC);
    edge_count_k<<<EB, 256, 0, stream>>>(eidx, es, cnt, part_sum);
    base1_k<<<NB, 256, 0, stream>>>(cnt, base_loc, total);
    base2_k<<<1, 1024, 0, stream>>>(total, part_sum, bstart, gstat);
    bin_k<<<EB, 256, 0, stream>>>(eidx, bstart, base_loc, binned);
    gemm_scale_k<<<(NN + 31) / 32, 256, 0, stream>>>(x, Wl, bl, es, gstat, wbuf);
    sort_agg_k<<<NB, 512, 0, stream>>>(wbuf, binned, bstart, bias, out);
}

// Round 8
// 104.572 us; speedup vs baseline: 4.5104x; 1.2549x over previous
//
#include <hip/hip_runtime.h>

#define NN 50000
#define EE 800000
#define HC 64
#define NB 782            // row buckets of 64 rows: 782*64 = 50048 >= NN
#define EB 256            // edge-pass blocks
#define EPB (EE / EB)     // 3125 edges per block, exact
#define BUCKET_CAP 2048   // mean bucket = 1024; fixed input, verified fits

__device__ __forceinline__ float dot4(float4 a, float4 b) {
    return fmaf(a.w, b.w, fmaf(a.z, b.z, fmaf(a.y, b.y, a.x * b.x)));
}
__device__ __forceinline__ void fma4(float& acc, float4 a, float4 b) {
    acc = fmaf(a.x, b.x, fmaf(a.y, b.y, fmaf(a.z, b.z, fmaf(a.w, b.w, acc))));
}

// ---------------------------------------------------------------------------
// precompute_k: v_topo[h][k] = sum_c att_topo[h,c]*W_topo[h*32+c][k]  (2x64)
//               cst2[h]     = sum_c att_topo[h,c]*b_topo[h*32+c]
// fused layout: [0..127] = v_topo, [128..129] = cst2
// (att_node is applied directly to xh accumulators in xh_score_k.)
// ---------------------------------------------------------------------------
__global__ __launch_bounds__(128) void precompute_k(
    const float* __restrict__ Wt, const float* __restrict__ bt,
    const float* __restrict__ attt, float* __restrict__ fused)
{
    int tid = threadIdx.x;
    int h = tid >> 6, k = tid & 63;
    float s = 0.f;
    for (int c = 0; c < 32; ++c)
        s = fmaf(attt[h * 32 + c], Wt[(h * 32 + c) * 64 + k], s);
    fused[tid] = s;
    if (tid < 2) {
        float s2 = 0.f;
        for (int c = 0; c < 32; ++c)
            s2 = fmaf(attt[tid * 32 + c], bt[tid * 32 + c], s2);
        fused[128 + tid] = s2;
    }
}

// ---------------------------------------------------------------------------
// xh_score_k: fused GEMM + attention score + topo passthrough.
//   xh[n,c] = x[n]·W_lin[c] + b_lin[c]          (written unscaled)
//   s[n,h]  = sum_c xh[n,c]*att_node[h,c] + v_topo[h]·topo[n] + cst2[h]
//   es[n,h] = exp(leaky_relu(s))
// 512 thr = 8 waves x (64 ch x 8 nodes). x AND W staged in LDS (coalesced
// global loads; compute reads are LDS broadcasts / per-lane stride-132).
// ---------------------------------------------------------------------------
__global__ __launch_bounds__(512) void xh_score_k(
    const float* __restrict__ x, const float* __restrict__ topo,
    const float* __restrict__ Wl, const float* __restrict__ bl,
    const float* __restrict__ attn, const float* __restrict__ fused,
    float* __restrict__ xh, float* __restrict__ es,
    float* __restrict__ topo_out)
{
    __shared__ float WLs[64 * 132];   // 33.8 KB
    __shared__ float xs[64 * 132];    // 33.8 KB
    int tid = threadIdx.x;
    const float4* Wl4 = (const float4*)Wl;
#pragma unroll
    for (int i0 = 0; i0 < 4; ++i0) {
        int i = i0 * 512 + tid;
        float4 v = Wl4[i];
        *(float4*)&WLs[(i >> 5) * 132 + ((i & 31) << 2)] = v;
    }
    int nblk = blockIdx.x * 64;
    int nv4 = (min(64, NN - nblk)) * 32;          // valid float4 count
    const float4* x4 = (const float4*)(x + (size_t)nblk * 128);
    for (int i = tid; i < nv4; i += 512) {
        float4 v = x4[i];
        *(float4*)&xs[(i >> 5) * 132 + ((i & 31) << 2)] = v;
    }
    __syncthreads();

    int w = tid >> 6, cl = tid & 63;
    int n0 = nblk + w * 8;
    if (n0 >= NN) return;                 // NN%8==0: whole wave valid or not

    float a[8];
    float b = bl[cl];
#pragma unroll
    for (int j = 0; j < 8; ++j) a[j] = b;
    const float* xr = &xs[(w * 8) * 132];
#pragma unroll 4
    for (int k4 = 0; k4 < 32; ++k4) {
        float4 wf = *(const float4*)&WLs[cl * 132 + (k4 << 2)];
#pragma unroll
        for (int j = 0; j < 8; ++j) {
            float4 v = *(const float4*)&xr[j * 132 + (k4 << 2)];
            fma4(a[j], wf, v);
        }
    }
    size_t ob = (size_t)n0 * 64 + cl;
#pragma unroll
    for (int j = 0; j < 8; ++j) xh[ob + j * 64] = a[j];

    // x-part scores: reduce a[j]*att_node within each 32-lane half (h=half)
    float an = attn[cl];
    float sc[8];
#pragma unroll
    for (int j = 0; j < 8; ++j) {
        float s = a[j] * an;
#pragma unroll
        for (int d = 16; d >= 1; d >>= 1) s += __shfl_xor(s, d, 64);
        sc[j] = s;
    }

    // topo rows: passthrough + topo-part scores (lane cl = row n0+(cl>>4), k4=cl&15)
    const float4* t4 = (const float4*)topo;
    float4* to4 = (float4*)topo_out;
    const float4* vt4 = (const float4*)fused;
    float4 vT0 = vt4[cl & 15], vT1 = vt4[16 + (cl & 15)];
    float4 B1 = t4[(size_t)n0 * 16 + cl];        // rows n0..n0+3
    float4 B2 = t4[(size_t)n0 * 16 + 64 + cl];   // rows n0+4..n0+7
    to4[(size_t)n0 * 16 + cl] = B1;
    to4[(size_t)n0 * 16 + 64 + cl] = B2;
    float q10 = dot4(B1, vT0), q11 = dot4(B1, vT1);
    float q20 = dot4(B2, vT0), q21 = dot4(B2, vT1);
#pragma unroll
    for (int d = 8; d >= 1; d >>= 1) {           // reduce within 16-lane groups
        q10 += __shfl_xor(q10, d, 64); q11 += __shfl_xor(q11, d, 64);
        q20 += __shfl_xor(q20, d, 64); q21 += __shfl_xor(q21, d, 64);
    }

    float cst0 = fused[128], cst1 = fused[129];
    float mys = 0.f;
#pragma unroll
    for (int j = 0; j < 8; ++j) {
        float xh0 = __shfl(sc[j], 0),  xh1 = __shfl(sc[j], 32);
        float qh0 = (j < 4) ? __shfl(q10, j * 16) : __shfl(q20, (j - 4) * 16);
        float qh1 = (j < 4) ? __shfl(q11, j * 16) : __shfl(q21, (j - 4) * 16);
        float s0 = xh0 + qh0 + cst0;
        float s1 = xh1 + qh1 + cst1;
        s0 = s0 > 0.f ? s0 : 0.2f * s0;
        s1 = s1 > 0.f ? s1 : 0.2f * s1;
        if ((cl >> 1) == j) mys = (cl & 1) ? s1 : s0;
    }
    if (cl < 16) es[(size_t)n0 * 2 + cl] = __expf(mys);
}

// ---------------------------------------------------------------------------
// edge_count_k: per-(block,bucket) counts in LDS + denominator partials.
// ---------------------------------------------------------------------------
__global__ __launch_bounds__(256) void edge_count_k(
    const int* __restrict__ eidx, const float* __restrict__ es,
    unsigned* __restrict__ cnt, float* __restrict__ part_sum)
{
    __shared__ unsigned bcnt[NB];
    int tid = threadIdx.x, blk = blockIdx.x;
    for (int i = tid; i < NB; i += 256) bcnt[i] = 0u;
    __syncthreads();

    const float2* es2 = (const float2*)es;
    int e0 = blk * EPB;
    float s0 = 0.f, s1 = 0.f;
    for (int e = e0 + tid; e < e0 + EPB; e += 256) {
        int r = eidx[e];
        int c = eidx[EE + e];
        atomicAdd(&bcnt[r >> 6], 1u);
        float2 ev = es2[c];
        s0 += ev.x; s1 += ev.y;
    }
#pragma unroll
    for (int d = 32; d; d >>= 1) {
        s0 += __shfl_xor(s0, d, 64);
        s1 += __shfl_xor(s1, d, 64);
    }
    __shared__ float sh[8];
    if ((tid & 63) == 0) { sh[(tid >> 6) * 2] = s0; sh[(tid >> 6) * 2 + 1] = s1; }
    __syncthreads();
    if (tid == 0) {
        for (int j = 1; j < 4; ++j) { s0 += sh[2 * j]; s1 += sh[2 * j + 1]; }
        part_sum[blk * 2] = s0; part_sum[blk * 2 + 1] = s1;
    }
    for (int i = tid; i < NB; i += 256) cnt[(size_t)i * EB + blk] = bcnt[i];
}

// ---------------------------------------------------------------------------
// base1_k: per bucket, exclusive scan of per-block counts -> base_local/total
// ---------------------------------------------------------------------------
__global__ __launch_bounds__(256) void base1_k(
    const unsigned* __restrict__ cnt, unsigned* __restrict__ base_local,
    unsigned* __restrict__ total)
{
    int b = blockIdx.x, tid = threadIdx.x, lane = tid & 63, wid = tid >> 6;
    unsigned v = cnt[(size_t)b * EB + tid], orig = v;
#pragma unroll
    for (int d = 1; d < 64; d <<= 1) {
        unsigned t = __shfl_up(v, d, 64);
        if (lane >= d) v += t;
    }
    __shared__ unsigned wtot[4];
    if (lane == 63) wtot[wid] = v;
    __syncthreads();
    unsigned wpre = 0;
    for (int j = 0; j < wid; ++j) wpre += wtot[j];
    base_local[(size_t)b * EB + tid] = wpre + v - orig;
    if (tid == 255) total[b] = wpre + v;
}

// ---------------------------------------------------------------------------
// base2_k: scan total[NB] -> bucket_start (+sentinel); part_sum -> gstat
// ---------------------------------------------------------------------------
__global__ __launch_bounds__(1024) void base2_k(
    const unsigned* __restrict__ total, const float* __restrict__ part_sum,
    unsigned* __restrict__ bucket_start, float* __restrict__ gstat)
{
    int tid = threadIdx.x, lane = tid & 63, wid = tid >> 6;
    unsigned v = (tid < NB) ? total[tid] : 0u, orig = v;
#pragma unroll
    for (int d = 1; d < 64; d <<= 1) {
        unsigned t = __shfl_up(v, d, 64);
        if (lane >= d) v += t;
    }
    __shared__ unsigned wtot[16];
    if (lane == 63) wtot[wid] = v;
    __syncthreads();
    unsigned wpre = 0;
    for (int j = 0; j < wid; ++j) wpre += wtot[j];
    if (tid < NB) {
        unsigned excl = wpre + v - orig;
        bucket_start[tid] = excl;
        if (tid == NB - 1) bucket_start[NB] = excl + orig;
    }
    float s0 = 0.f, s1 = 0.f;
    if (tid < EB) { s0 = part_sum[tid * 2]; s1 = part_sum[tid * 2 + 1]; }
#pragma unroll
    for (int d = 32; d; d >>= 1) {
        s0 += __shfl_xor(s0, d, 64);
        s1 += __shfl_xor(s1, d, 64);
    }
    __shared__ float sh2[32];
    if (lane == 0) { sh2[wid * 2] = s0; sh2[wid * 2 + 1] = s1; }
    __syncthreads();
    if (tid == 0) {
        for (int j = 1; j < 4; ++j) { s0 += sh2[2 * j]; s1 += sh2[2 * j + 1]; }
        gstat[0] = 1.f / s0; gstat[1] = 1.f / s1;
    }
}

// ---------------------------------------------------------------------------
// bin_k: place packed (row<<16)|col into bucket windows; LDS cursors only.
// ---------------------------------------------------------------------------
__global__ __launch_bounds__(256) void bin_k(
    const int* __restrict__ eidx, const unsigned* __restrict__ bucket_start,
    const unsigned* __restrict__ base_local, unsigned* __restrict__ binned)
{
    __shared__ unsigned cur[NB];
    int tid = threadIdx.x, blk = blockIdx.x;
    for (int i = tid; i < NB; i += 256)
        cur[i] = bucket_start[i] + base_local[(size_t)i * EB + blk];
    __syncthreads();
    int e0 = blk * EPB;
    for (int e = e0 + tid; e < e0 + EPB; e += 256) {
        unsigned r = (unsigned)eidx[e];
        unsigned c = (unsigned)eidx[EE + e];
        unsigned slot = atomicAdd(&cur[r >> 6], 1u);   // LDS atomic
        binned[slot] = (r << 16) | c;
    }
}

// ---------------------------------------------------------------------------
// sort_agg_k: one block (512 thr) per 64-row bucket.
//   counting-sort cols row-wise in LDS, then wave w owns rows 8w..8w+7:
//   register accumulation of xh[c]*es[c,h], row-final *1/denom + bias.
// ---------------------------------------------------------------------------
__global__ __launch_bounds__(512) void sort_agg_k(
    const float* __restrict__ xhsrc, const float* __restrict__ es,
    const unsigned* __restrict__ binned, const unsigned* __restrict__ bucket_start,
    const float* __restrict__ gstat, const float* __restrict__ bias,
    float* __restrict__ out)
{
    __shared__ unsigned ecol[BUCKET_CAP];        // 8 KB packed (r<<16)|c
    __shared__ unsigned short scol[BUCKET_CAP];  // 4 KB row-sorted cols
    __shared__ unsigned hist[65];
    __shared__ unsigned rbase[65];
    int tid = threadIdx.x, lane = tid & 63, w = tid >> 6;
    int b = blockIdx.x, r0 = b << 6;
    unsigned start = bucket_start[b], end = bucket_start[b + 1];
    int m = (int)(end - start);

    if (tid < 65) hist[tid] = 0u;
    __syncthreads();
    for (int i = tid; i < m; i += 512) {
        unsigned e = binned[start + i];
        ecol[i] = e;
        atomicAdd(&hist[(e >> 16) - (unsigned)r0], 1u);
    }
    __syncthreads();
    if (tid < 64) {
        unsigned v = hist[tid], xv = v;
#pragma unroll
        for (int d = 1; d < 64; d <<= 1) {
            unsigned t = __shfl_up(xv, d, 64);
            if (lane >= d) xv += t;
        }
        rbase[tid] = xv - v;
        hist[tid] = xv - v;
        if (tid == 63) rbase[64] = xv;
    }
    __syncthreads();
    for (int i = tid; i < m; i += 512) {
        unsigned e = ecol[i];
        unsigned slot = atomicAdd(&hist[(e >> 16) - (unsigned)r0], 1u);
        scol[slot] = (unsigned short)(e & 0xffffu);
    }
    __syncthreads();

    int h = lane >> 5;
    float gi = gstat[h];
    float bv = bias[lane];
    for (int rr = w * 8; rr < w * 8 + 8; ++rr) {
        int r = r0 + rr;
        if (r >= NN) break;
        unsigned st = rbase[rr], en = rbase[rr + 1];
        float acc = 0.f;
        unsigned j = st;
        for (; j + 4 <= en; j += 4) {
            unsigned c0 = scol[j],     c1 = scol[j + 1];
            unsigned c2 = scol[j + 2], c3 = scol[j + 3];
            float e0 = es[(c0 << 1) + h], e1 = es[(c1 << 1) + h];
            float e2 = es[(c2 << 1) + h], e3 = es[(c3 << 1) + h];
            acc = fmaf(xhsrc[(size_t)c0 * 64 + lane], e0, acc);
            acc = fmaf(xhsrc[(size_t)c1 * 64 + lane], e1, acc);
            acc = fmaf(xhsrc[(size_t)c2 * 64 + lane], e2, acc);
            acc = fmaf(xhsrc[(size_t)c3 * 64 + lane], e3, acc);
        }
        for (; j < en; ++j) {
            unsigned c = scol[j];
            acc = fmaf(xhsrc[(size_t)c * 64 + lane], es[(c << 1) + h], acc);
        }
        out[(size_t)r * 64 + lane] = fmaf(acc, gi, bv);
    }
}

// ---------------------------------------------------------------------------
extern "C" void kernel_launch(void* const* d_in, const int* in_sizes, int n_in,
                              void* d_out, int out_size, void* d_ws, size_t ws_size,
                              hipStream_t stream)
{
    const float* x    = (const float*)d_in[0];
    const int*   eidx = (const int*)d_in[1];
    const float* topo = (const float*)d_in[2];
    const float* Wl   = (const float*)d_in[3];
    const float* bl   = (const float*)d_in[4];
    const float* Wt   = (const float*)d_in[5];
    const float* bt   = (const float*)d_in[6];
    const float* attn = (const float*)d_in[7];
    const float* attt = (const float*)d_in[8];
    const float* bias = (const float*)d_in[9];
    float* out = (float*)d_out;

    char* p = (char*)d_ws;
    auto alloc = [&](size_t bytes) {
        char* r = p;
        p += (bytes + 511) & ~size_t(511);
        return r;
    };
    float*    xhbuf     = (float*)   alloc((size_t)NN * HC * sizeof(float));   // 12.8 MB
    float*    es        = (float*)   alloc((size_t)NN * 2 * sizeof(float));    // 400 KB
    unsigned* binned    = (unsigned*)alloc((size_t)EE * sizeof(unsigned));     // 3.2 MB
    unsigned* cnt       = (unsigned*)alloc((size_t)NB * EB * sizeof(unsigned));// 0.8 MB
    unsigned* base_loc  = (unsigned*)alloc((size_t)NB * EB * sizeof(unsigned));// 0.8 MB
    unsigned* total     = (unsigned*)alloc((size_t)NB * sizeof(unsigned));
    unsigned* bstart    = (unsigned*)alloc((size_t)(NB + 1) * sizeof(unsigned));
    float*    part_sum  = (float*)   alloc(EB * 2 * sizeof(float));
    float*    gstat     = (float*)   alloc(4 * sizeof(float));
    float*    fused     = (float*)   alloc(512 * sizeof(float));

    precompute_k<<<1, 128, 0, stream>>>(Wt, bt, attt, fused);
    xh_score_k<<<NB, 512, 0, stream>>>(x, topo, Wl, bl, attn, fused,
                                       xhbuf, es, out + (size_t)NN * HC);
    edge_count_k<<<EB, 256, 0, stream>>>(eidx, es, cnt, part_sum);
    base1_k<<<NB, 256, 0, stream>>>(cnt, base_loc, total);
    base2_k<<<1, 1024, 0, stream>>>(total, part_sum, bstart, gstat);
    bin_k<<<EB, 256, 0, stream>>>(eidx, bstart, base_loc, binned);
    sort_agg_k<<<NB, 512, 0, stream>>>(xhbuf, es, binned, bstart, gstat, bias, out);
}

// Round 9
// 99.855 us; speedup vs baseline: 4.7235x; 1.0472x over previous
//
#include <hip/hip_runtime.h>

#define NN 50000
#define EE 800000
#define HC 64
#define NB 782            // row buckets of 64 rows: 782*64 = 50048 >= NN
#define EB 256            // edge-pass blocks
#define EPB (EE / EB)     // 3125 edges per block, exact
#define BUCKET_CAP 2048   // mean bucket = 1024; fixed input, verified fits
#define GB 391            // gemm blocks: 391*128 = 50048 >= NN

__device__ __forceinline__ float dot4(float4 a, float4 b) {
    return fmaf(a.w, b.w, fmaf(a.z, b.z, fmaf(a.y, b.y, a.x * b.x)));
}
__device__ __forceinline__ void fma4(float& acc, float4 a, float4 b) {
    acc = fmaf(a.x, b.x, fmaf(a.y, b.y, fmaf(a.z, b.z, fmaf(a.w, b.w, acc))));
}

// ---------------------------------------------------------------------------
// precompute_k: v_topo[h][k] = sum_c att_topo[h,c]*W_topo[h*32+c][k]  (2x64)
//               cst2[h]     = sum_c att_topo[h,c]*b_topo[h*32+c]
// fused layout: [0..127] = v_topo, [128..129] = cst2
// ---------------------------------------------------------------------------
__global__ __launch_bounds__(128) void precompute_k(
    const float* __restrict__ Wt, const float* __restrict__ bt,
    const float* __restrict__ attt, float* __restrict__ fused)
{
    int tid = threadIdx.x;
    int h = tid >> 6, k = tid & 63;
    float s = 0.f;
    for (int c = 0; c < 32; ++c)
        s = fmaf(attt[h * 32 + c], Wt[(h * 32 + c) * 64 + k], s);
    fused[tid] = s;
    if (tid < 2) {
        float s2 = 0.f;
        for (int c = 0; c < 32; ++c)
            s2 = fmaf(attt[tid * 32 + c], bt[tid * 32 + c], s2);
        fused[128 + tid] = s2;
    }
}

// ---------------------------------------------------------------------------
// xh_score_k: fused GEMM + attention score + topo passthrough.
// 2D register tiling: block = 256 thr = 4 waves; wave = 64ch x 32 nodes;
// lane (i,j) in 8x8 grid owns 8 channels (8i..8i+7) x 4 nodes (4j..4j+3).
// Per k4-step: 8 ds_read_b128 (W, row-permuted LDS, conflict-free) +
// 4 global b128 (x, lane-duplicated -> coalesced) feed 512 VALU cycles.
//   xh[n,c] = x[n]·W_lin[c] + b_lin[c]          (written unscaled)
//   es[n,h] = exp(lrelu(sum_c xh*att_node[h] + v_topo[h]·topo[n] + cst2[h]))
// ---------------------------------------------------------------------------
__global__ __launch_bounds__(256) void xh_score_k(
    const float* __restrict__ x, const float* __restrict__ topo,
    const float* __restrict__ Wl, const float* __restrict__ bl,
    const float* __restrict__ attn, const float* __restrict__ fused,
    float* __restrict__ xh, float* __restrict__ es,
    float* __restrict__ topo_out)
{
    __shared__ float WLs[64 * 33 * 4];   // 33.8 KB, rows permuted, stride 33 f4
    __shared__ float sxs[4][32][2];      // per-wave x-part scores
    int tid = threadIdx.x;
    const float4* Wl4 = (const float4*)Wl;
#pragma unroll
    for (int p = 0; p < 8; ++p) {
        int idx = p * 256 + tid;          // f4 index: c = idx>>5, k4 = idx&31
        int c = idx >> 5, k4 = idx & 31;
        int slot = ((c & 7) << 3) + (c >> 3);   // row permutation
        *(float4*)&WLs[(slot * 33 + k4) << 2] = Wl4[idx];
    }
    __syncthreads();

    int w = tid >> 6, l = tid & 63;
    int i = l & 7, j = l >> 3;
    int n0w = blockIdx.x * 128 + w * 32;

    float4 bf0 = ((const float4*)bl)[2 * i],   bf1 = ((const float4*)bl)[2 * i + 1];
    float4 af0 = ((const float4*)attn)[2 * i], af1 = ((const float4*)attn)[2 * i + 1];

    float acc[4][8];
#pragma unroll
    for (int r = 0; r < 4; ++r) {
        acc[r][0] = bf0.x; acc[r][1] = bf0.y; acc[r][2] = bf0.z; acc[r][3] = bf0.w;
        acc[r][4] = bf1.x; acc[r][5] = bf1.y; acc[r][6] = bf1.z; acc[r][7] = bf1.w;
    }
    const float* xp[4];
#pragma unroll
    for (int r = 0; r < 4; ++r) {
        int row = n0w + 4 * j + r;
        xp[r] = x + (size_t)(row < NN ? row : NN - 1) * 128;
    }
    const float* wp[8];
#pragma unroll
    for (int s = 0; s < 8; ++s) wp[s] = &WLs[(((s << 3) + i) * 33) << 2];

    for (int ko = 0; ko < 4; ++ko) {
#pragma unroll
        for (int kk = 0; kk < 8; ++kk) {
            float4 xv[4], wv[8];
#pragma unroll
            for (int r = 0; r < 4; ++r) xv[r] = *(const float4*)(xp[r] + kk * 4);
#pragma unroll
            for (int s = 0; s < 8; ++s) wv[s] = *(const float4*)(wp[s] + kk * 4);
#pragma unroll
            for (int r = 0; r < 4; ++r)
#pragma unroll
                for (int s = 0; s < 8; ++s)
                    fma4(acc[r][s], wv[s], xv[r]);
        }
#pragma unroll
        for (int r = 0; r < 4; ++r) xp[r] += 32;
#pragma unroll
        for (int s = 0; s < 8; ++s) wp[s] += 32;
    }

    // xh store: 2 f4 per row, rows 4j..4j+3; lanes i=0..7 cover 64 ch (256B)
#pragma unroll
    for (int r = 0; r < 4; ++r) {
        int row = n0w + 4 * j + r;
        if (row < NN) {
            float4* dst = (float4*)(xh + (size_t)row * 64 + 8 * i);
            dst[0] = make_float4(acc[r][0], acc[r][1], acc[r][2], acc[r][3]);
            dst[1] = make_float4(acc[r][4], acc[r][5], acc[r][6], acc[r][7]);
        }
    }

    // x-part score: lane's 8 channels all belong to head h = i>>2;
    // reduce over the 4 lanes with same (j, i>>2) via xor on i bits 0,1.
#pragma unroll
    for (int r = 0; r < 4; ++r) {
        float ps = acc[r][0]*af0.x + acc[r][1]*af0.y + acc[r][2]*af0.z + acc[r][3]*af0.w
                 + acc[r][4]*af1.x + acc[r][5]*af1.y + acc[r][6]*af1.z + acc[r][7]*af1.w;
        ps += __shfl_xor(ps, 1, 64);
        ps += __shfl_xor(ps, 2, 64);
        if ((i & 3) == 0) sxs[w][4 * j + r][i >> 2] = ps;
    }
    __builtin_amdgcn_wave_barrier();   // pin LDS write -> read order (in-wave)

    // topo: passthrough + topo-part score; 16-lane groups own rows
    const float4* t4 = (const float4*)topo;
    float4* to4 = (float4*)topo_out;
    const float4* vt4 = (const float4*)fused;
    int k4t = l & 15, g = l >> 4;
    float4 vT0 = vt4[k4t], vT1 = vt4[16 + k4t];
    float cst0 = fused[128], cst1 = fused[129];
#pragma unroll
    for (int p = 0; p < 8; ++p) {
        int row = n0w + 4 * p + g;
        size_t fi = (size_t)(row < NN ? row : NN - 1) * 16 + k4t;
        float4 B = t4[fi];
        if (row < NN) to4[(size_t)row * 16 + k4t] = B;
        float q0 = dot4(B, vT0), q1 = dot4(B, vT1);
#pragma unroll
        for (int d = 8; d >= 1; d >>= 1) {
            q0 += __shfl_xor(q0, d, 64);
            q1 += __shfl_xor(q1, d, 64);
        }
        if (k4t == 0 && row < NN) {
            int rl = 4 * p + g;
            float s0 = sxs[w][rl][0] + q0 + cst0;
            float s1 = sxs[w][rl][1] + q1 + cst1;
            s0 = s0 > 0.f ? s0 : 0.2f * s0;
            s1 = s1 > 0.f ? s1 : 0.2f * s1;
            es[(size_t)row * 2]     = __expf(s0);
            es[(size_t)row * 2 + 1] = __expf(s1);
        }
    }
}

// ---------------------------------------------------------------------------
// edge_count_k: per-(block,bucket) counts in LDS + denominator partials.
// ---------------------------------------------------------------------------
__global__ __launch_bounds__(256) void edge_count_k(
    const int* __restrict__ eidx, const float* __restrict__ es,
    unsigned* __restrict__ cnt, float* __restrict__ part_sum)
{
    __shared__ unsigned bcnt[NB];
    int tid = threadIdx.x, blk = blockIdx.x;
    for (int i = tid; i < NB; i += 256) bcnt[i] = 0u;
    __syncthreads();

    const float2* es2 = (const float2*)es;
    int e0 = blk * EPB;
    float s0 = 0.f, s1 = 0.f;
    for (int e = e0 + tid; e < e0 + EPB; e += 256) {
        int r = eidx[e];
        int c = eidx[EE + e];
        atomicAdd(&bcnt[r >> 6], 1u);
        float2 ev = es2[c];
        s0 += ev.x; s1 += ev.y;
    }
#pragma unroll
    for (int d = 32; d; d >>= 1) {
        s0 += __shfl_xor(s0, d, 64);
        s1 += __shfl_xor(s1, d, 64);
    }
    __shared__ float sh[8];
    if ((tid & 63) == 0) { sh[(tid >> 6) * 2] = s0; sh[(tid >> 6) * 2 + 1] = s1; }
    __syncthreads();
    if (tid == 0) {
        for (int j = 1; j < 4; ++j) { s0 += sh[2 * j]; s1 += sh[2 * j + 1]; }
        part_sum[blk * 2] = s0; part_sum[blk * 2 + 1] = s1;
    }
    for (int i = tid; i < NB; i += 256) cnt[(size_t)i * EB + blk] = bcnt[i];
}

// ---------------------------------------------------------------------------
// base1_k: per bucket, exclusive scan of per-block counts -> base_local/total
// ---------------------------------------------------------------------------
__global__ __launch_bounds__(256) void base1_k(
    const unsigned* __restrict__ cnt, unsigned* __restrict__ base_local,
    unsigned* __restrict__ total)
{
    int b = blockIdx.x, tid = threadIdx.x, lane = tid & 63, wid = tid >> 6;
    unsigned v = cnt[(size_t)b * EB + tid], orig = v;
#pragma unroll
    for (int d = 1; d < 64; d <<= 1) {
        unsigned t = __shfl_up(v, d, 64);
        if (lane >= d) v += t;
    }
    __shared__ unsigned wtot[4];
    if (lane == 63) wtot[wid] = v;
    __syncthreads();
    unsigned wpre = 0;
    for (int j = 0; j < wid; ++j) wpre += wtot[j];
    base_local[(size_t)b * EB + tid] = wpre + v - orig;
    if (tid == 255) total[b] = wpre + v;
}

// ---------------------------------------------------------------------------
// base2_k: scan total[NB] -> bucket_start (+sentinel); part_sum -> gstat
// ---------------------------------------------------------------------------
__global__ __launch_bounds__(1024) void base2_k(
    const unsigned* __restrict__ total, const float* __restrict__ part_sum,
    unsigned* __restrict__ bucket_start, float* __restrict__ gstat)
{
    int tid = threadIdx.x, lane = tid & 63, wid = tid >> 6;
    unsigned v = (tid < NB) ? total[tid] : 0u, orig = v;
#pragma unroll
    for (int d = 1; d < 64; d <<= 1) {
        unsigned t = __shfl_up(v, d, 64);
        if (lane >= d) v += t;
    }
    __shared__ unsigned wtot[16];
    if (lane == 63) wtot[wid] = v;
    __syncthreads();
    unsigned wpre = 0;
    for (int j = 0; j < wid; ++j) wpre += wtot[j];
    if (tid < NB) {
        unsigned excl = wpre + v - orig;
        bucket_start[tid] = excl;
        if (tid == NB - 1) bucket_start[NB] = excl + orig;
    }
    float s0 = 0.f, s1 = 0.f;
    if (tid < EB) { s0 = part_sum[tid * 2]; s1 = part_sum[tid * 2 + 1]; }
#pragma unroll
    for (int d = 32; d; d >>= 1) {
        s0 += __shfl_xor(s0, d, 64);
        s1 += __shfl_xor(s1, d, 64);
    }
    __shared__ float sh2[32];
    if (lane == 0) { sh2[wid * 2] = s0; sh2[wid * 2 + 1] = s1; }
    __syncthreads();
    if (tid == 0) {
        for (int j = 1; j < 4; ++j) { s0 += sh2[2 * j]; s1 += sh2[2 * j + 1]; }
        gstat[0] = 1.f / s0; gstat[1] = 1.f / s1;
    }
}

// ---------------------------------------------------------------------------
// bin_k: place packed (row<<16)|col into bucket windows; LDS cursors only.
// ---------------------------------------------------------------------------
__global__ __launch_bounds__(256) void bin_k(
    const int* __restrict__ eidx, const unsigned* __restrict__ bucket_start,
    const unsigned* __restrict__ base_local, unsigned* __restrict__ binned)
{
    __shared__ unsigned cur[NB];
    int tid = threadIdx.x, blk = blockIdx.x;
    for (int i = tid; i < NB; i += 256)
        cur[i] = bucket_start[i] + base_local[(size_t)i * EB + blk];
    __syncthreads();
    int e0 = blk * EPB;
    for (int e = e0 + tid; e < e0 + EPB; e += 256) {
        unsigned r = (unsigned)eidx[e];
        unsigned c = (unsigned)eidx[EE + e];
        unsigned slot = atomicAdd(&cur[r >> 6], 1u);   // LDS atomic
        binned[slot] = (r << 16) | c;
    }
}

// ---------------------------------------------------------------------------
// sort_agg_k: one block (512 thr) per 64-row bucket.
//   counting-sort cols row-wise in LDS, then wave w owns rows 8w..8w+7:
//   register accumulation of xh[c]*es[c,h], row-final *1/denom + bias.
// ---------------------------------------------------------------------------
__global__ __launch_bounds__(512) void sort_agg_k(
    const float* __restrict__ xhsrc, const float* __restrict__ es,
    const unsigned* __restrict__ binned, const unsigned* __restrict__ bucket_start,
    const float* __restrict__ gstat, const float* __restrict__ bias,
    float* __restrict__ out)
{
    __shared__ unsigned ecol[BUCKET_CAP];        // 8 KB packed (r<<16)|c
    __shared__ unsigned short scol[BUCKET_CAP];  // 4 KB row-sorted cols
    __shared__ unsigned hist[65];
    __shared__ unsigned rbase[65];
    int tid = threadIdx.x, lane = tid & 63, w = tid >> 6;
    int b = blockIdx.x, r0 = b << 6;
    unsigned start = bucket_start[b], end = bucket_start[b + 1];
    int m = (int)(end - start);

    if (tid < 65) hist[tid] = 0u;
    __syncthreads();
    for (int i = tid; i < m; i += 512) {
        unsigned e = binned[start + i];
        ecol[i] = e;
        atomicAdd(&hist[(e >> 16) - (unsigned)r0], 1u);
    }
    __syncthreads();
    if (tid < 64) {
        unsigned v = hist[tid], xv = v;
#pragma unroll
        for (int d = 1; d < 64; d <<= 1) {
            unsigned t = __shfl_up(xv, d, 64);
            if (lane >= d) xv += t;
        }
        rbase[tid] = xv - v;
        hist[tid] = xv - v;
        if (tid == 63) rbase[64] = xv;
    }
    __syncthreads();
    for (int i = tid; i < m; i += 512) {
        unsigned e = ecol[i];
        unsigned slot = atomicAdd(&hist[(e >> 16) - (unsigned)r0], 1u);
        scol[slot] = (unsigned short)(e & 0xffffu);
    }
    __syncthreads();

    int h = lane >> 5;
    float gi = gstat[h];
    float bv = bias[lane];
    for (int rr = w * 8; rr < w * 8 + 8; ++rr) {
        int r = r0 + rr;
        if (r >= NN) break;
        unsigned st = rbase[rr], en = rbase[rr + 1];
        float acc = 0.f;
        unsigned j = st;
        for (; j + 4 <= en; j += 4) {
            unsigned c0 = scol[j],     c1 = scol[j + 1];
            unsigned c2 = scol[j + 2], c3 = scol[j + 3];
            float e0 = es[(c0 << 1) + h], e1 = es[(c1 << 1) + h];
            float e2 = es[(c2 << 1) + h], e3 = es[(c3 << 1) + h];
            acc = fmaf(xhsrc[(size_t)c0 * 64 + lane], e0, acc);
            acc = fmaf(xhsrc[(size_t)c1 * 64 + lane], e1, acc);
            acc = fmaf(xhsrc[(size_t)c2 * 64 + lane], e2, acc);
            acc = fmaf(xhsrc[(size_t)c3 * 64 + lane], e3, acc);
        }
        for (; j < en; ++j) {
            unsigned c = scol[j];
            acc = fmaf(xhsrc[(size_t)c * 64 + lane], es[(c << 1) + h], acc);
        }
        out[(size_t)r * 64 + lane] = fmaf(acc, gi, bv);
    }
}

// ---------------------------------------------------------------------------
extern "C" void kernel_launch(void* const* d_in, const int* in_sizes, int n_in,
                              void* d_out, int out_size, void* d_ws, size_t ws_size,
                              hipStream_t stream)
{
    const float* x    = (const float*)d_in[0];
    const int*   eidx = (const int*)d_in[1];
    const float* topo = (const float*)d_in[2];
    const float* Wl   = (const float*)d_in[3];
    const float* bl   = (const float*)d_in[4];
    const float* Wt   = (const float*)d_in[5];
    const float* bt   = (const float*)d_in[6];
    const float* attn = (const float*)d_in[7];
    const float* attt = (const float*)d_in[8];
    const float* bias = (const float*)d_in[9];
    float* out = (float*)d_out;

    char* p = (char*)d_ws;
    auto alloc = [&](size_t bytes) {
        char* r = p;
        p += (bytes + 511) & ~size_t(511);
        return r;
    };
    float*    xhbuf     = (float*)   alloc((size_t)NN * HC * sizeof(float));   // 12.8 MB
    float*    es        = (float*)   alloc((size_t)NN * 2 * sizeof(float));    // 400 KB
    unsigned* binned    = (unsigned*)alloc((size_t)EE * sizeof(unsigned));     // 3.2 MB
    unsigned* cnt       = (unsigned*)alloc((size_t)NB * EB * sizeof(unsigned));// 0.8 MB
    unsigned* base_loc  = (unsigned*)alloc((size_t)NB * EB * sizeof(unsigned));// 0.8 MB
    unsigned* total     = (unsigned*)alloc((size_t)NB * sizeof(unsigned));
    unsigned* bstart    = (unsigned*)alloc((size_t)(NB + 1) * sizeof(unsigned));
    float*    part_sum  = (float*)   alloc(EB * 2 * sizeof(float));
    float*    gstat     = (float*)   alloc(4 * sizeof(float));
    float*    fused     = (float*)   alloc(512 * sizeof(float));

    precompute_k<<<1, 128, 0, stream>>>(Wt, bt, attt, fused);
    xh_score_k<<<GB, 256, 0, stream>>>(x, topo, Wl, bl, attn, fused,
                                       xhbuf, es, out + (size_t)NN * HC);
    edge_count_k<<<EB, 256, 0, stream>>>(eidx, es, cnt, part_sum);
    base1_k<<<NB, 256, 0, stream>>>(cnt, base_loc, total);
    base2_k<<<1, 1024, 0, stream>>>(total, part_sum, bstart, gstat);
    bin_k<<<EB, 256, 0, stream>>>(eidx, bstart, base_loc, binned);
    sort_agg_k<<<NB, 512, 0, stream>>>(xhbuf, es, binned, bstart, gstat, bias, out);
}